// Round 2
// baseline (351.585 us; speedup 1.0000x reference)
//
#include <hip/hip_runtime.h>
#include <hip/hip_bf16.h>
#include <cstdint>

typedef __bf16 bf16;
typedef bf16 bf16x8 __attribute__((ext_vector_type(8)));
typedef bf16 bf16x4 __attribute__((ext_vector_type(4)));
typedef float f32x4 __attribute__((ext_vector_type(4)));

#define MFMA16(a, b, c) __builtin_amdgcn_mfma_f32_16x16x32_bf16(a, b, c, 0, 0, 0)

struct rawF { f32x4 a, b; };
__device__ inline rawF ldr(const float* p) {
  rawF r; r.a = *(const f32x4*)p; r.b = *(const f32x4*)(p + 4); return r;
}
__device__ inline bf16x8 ldr(const bf16* p) { return *(const bf16x8*)p; }
__device__ inline bf16x8 cv(const rawF& r) {
  bf16x8 o;
#pragma unroll
  for (int i = 0; i < 4; ++i) { o[i] = (bf16)r.a[i]; o[i + 4] = (bf16)r.b[i]; }
  return o;
}
__device__ inline bf16x8 cv(const bf16x8& r) { return r; }
__device__ inline void stC(bf16* C, size_t i, float v) { C[i] = (bf16)v; }
__device__ inline void stC(float* C, size_t i, float v) { C[i] = v; }

// ---- prep: transpose-convert 4 weights fp32 [K][N] -> bf16 [N][K] ----
__global__ __launch_bounds__(256) void prep_wt(const float* __restrict__ W0,
                                               const float* __restrict__ W1,
                                               const float* __restrict__ W2,
                                               const float* __restrict__ W3,
                                               bf16* __restrict__ Wt, int n) {
  const float* Ws[4] = {W0, W1, W2, W3};
  const float* W = Ws[blockIdx.z];
  bf16* out = Wt + (size_t)blockIdx.z * n * n;
  __shared__ bf16 t[32][33];
  int bx = blockIdx.x * 32, by = blockIdx.y * 32;
  int tx = threadIdx.x & 31, ty = threadIdx.x >> 5;
#pragma unroll
  for (int i = 0; i < 32; i += 8)
    t[ty + i][tx] = (bf16)W[(size_t)(by + ty + i) * n + bx + tx];
  __syncthreads();
#pragma unroll
  for (int i = 0; i < 32; i += 8)
    out[(size_t)(bx + ty + i) * n + by + tx] = t[tx][ty + i];
}

// ---- transpose V bf16 [b*s][D] -> Vt [bh][hd][2048] ----
__global__ __launch_bounds__(256) void vtrans(const bf16* __restrict__ V, bf16* __restrict__ Vt) {
  constexpr int Sn = 2048, Dn = 1024;
  __shared__ bf16 t[32][33];
  int s0 = blockIdx.x * 32, hd0 = blockIdx.y * 32, bh = blockIdx.z;
  int b = bh >> 4, h = bh & 15;
  int tx = threadIdx.x & 31, ty = threadIdx.x >> 5;
#pragma unroll
  for (int i = 0; i < 32; i += 8)
    t[ty + i][tx] = V[(size_t)(b * Sn + s0 + ty + i) * Dn + h * 64 + hd0 + tx];
  __syncthreads();
#pragma unroll
  for (int i = 0; i < 32; i += 8)
    Vt[(size_t)bh * 64 * Sn + (size_t)(hd0 + ty + i) * Sn + s0 + tx] = t[tx][ty + i];
}

// ---- GEMM C[M,N] = A[M,K] @ B; register-prefetched k-loop; 3 outputs via blockIdx.y ----
template <typename TA, typename TC, bool BT>
__global__ __launch_bounds__(256) void gemm3(const TA* __restrict__ A,
                                             const void* __restrict__ B0p,
                                             const void* __restrict__ B1p,
                                             const void* __restrict__ B2p,
                                             TC* __restrict__ C0, TC* __restrict__ C1,
                                             TC* __restrict__ C2, int M, int N, int K, int nblk) {
  constexpr int LDA = 40;
  constexpr int LDB = BT ? 40 : 32;
  __shared__ bf16 As[128 * LDA];
  __shared__ bf16 Bs[128 * LDB];
  int tid = threadIdx.x, wave = tid >> 6, lane = tid & 63;
  int la = lane & 15, quad = lane >> 4;
  int wr = (wave >> 1) * 64, wc = (wave & 1) * 64;
  int by = blockIdx.y;
  int sel = by / nblk;
  int n0 = (by - sel * nblk) * 128;
  const void* Bp = sel == 0 ? B0p : (sel == 1 ? B1p : B2p);
  TC* C = sel == 0 ? C0 : (sel == 1 ? C1 : C2);
  const TA* Ab = A + (size_t)blockIdx.x * 128 * K;
  using TB = typename std::conditional<BT, bf16, float>::type;
  const TB* Bm = (const TB*)Bp;

  // per-p staging indices
  int ar[2], ac[2], br[2], bc[2];
#pragma unroll
  for (int p = 0; p < 2; ++p) {
    int li = (tid + p * 256) * 8;
    ar[p] = li >> 5; ac[p] = li & 31;       // A: row, kcol
    if (BT) { br[p] = li >> 5; bc[p] = li & 31; }    // B^T: nrow, kcol
    else    { br[p] = li >> 7; bc[p] = li & 127; }   // B: krow, ncol
  }

  f32x4 zero = {0.f, 0.f, 0.f, 0.f};
  f32x4 acc[4][4];
#pragma unroll
  for (int i = 0; i < 4; ++i)
#pragma unroll
    for (int j = 0; j < 4; ++j) acc[i][j] = zero;

  decltype(ldr((const TA*)nullptr)) pa[2];
  decltype(ldr((const TB*)nullptr)) pb[2];
#pragma unroll
  for (int p = 0; p < 2; ++p) {
    pa[p] = ldr(&Ab[(size_t)ar[p] * K + ac[p]]);
    if (BT) pb[p] = ldr(&Bm[(size_t)(n0 + br[p]) * K + bc[p]]);
    else    pb[p] = ldr(&Bm[(size_t)br[p] * N + n0 + bc[p]]);
  }

  for (int k0 = 0; k0 < K; k0 += 32) {
#pragma unroll
    for (int p = 0; p < 2; ++p) {
      *(bf16x8*)&As[ar[p] * LDA + ac[p]] = cv(pa[p]);
      if constexpr (BT) {
        *(bf16x8*)&Bs[br[p] * LDB + bc[p]] = cv(pb[p]);
      } else {
        bf16x8 v = cv(pb[p]);
        int kx = br[p] ^ (((bc[p] >> 3) & 3) << 3);
#pragma unroll
        for (int j = 0; j < 8; ++j) Bs[(bc[p] + j) * 32 + kx] = v[j];
      }
    }
    __syncthreads();
    int k1 = k0 + 32;
    if (k1 < K) {
#pragma unroll
      for (int p = 0; p < 2; ++p) {
        pa[p] = ldr(&Ab[(size_t)ar[p] * K + k1 + ac[p]]);
        if (BT) pb[p] = ldr(&Bm[(size_t)(n0 + br[p]) * K + k1 + bc[p]]);
        else    pb[p] = ldr(&Bm[(size_t)(k1 + br[p]) * N + n0 + bc[p]]);
      }
    }
    bf16x8 af[4], bfr[4];
#pragma unroll
    for (int i = 0; i < 4; ++i)
      af[i] = *(const bf16x8*)&As[(wr + i * 16 + la) * LDA + quad * 8];
#pragma unroll
    for (int j = 0; j < 4; ++j) {
      int nr = wc + j * 16 + la;
      if constexpr (BT)
        bfr[j] = *(const bf16x8*)&Bs[nr * LDB + quad * 8];
      else
        bfr[j] = *(const bf16x8*)&Bs[nr * 32 + ((quad * 8) ^ (((nr >> 3) & 3) << 3))];
    }
#pragma unroll
    for (int i = 0; i < 4; ++i)
#pragma unroll
      for (int j = 0; j < 4; ++j) acc[i][j] = MFMA16(af[i], bfr[j], acc[i][j]);
    __syncthreads();
  }
#pragma unroll
  for (int i = 0; i < 4; ++i) {
#pragma unroll
    for (int j = 0; j < 4; ++j) {
      int col = n0 + wc + j * 16 + la;
#pragma unroll
      for (int r = 0; r < 4; ++r) {
        int row = blockIdx.x * 128 + wr + i * 16 + quad * 4 + r;
        stC(C, (size_t)row * N + col, acc[i][j][r]);
      }
    }
  }
}

// ---- flash attention, causal, HD=64; transposed scores (S^T = K@Q^T) ----
// Fragment-major LDS layouts: each MFMA fragment read covers a contiguous
// 1024B block (coverage-optimal, zero bank conflict); XOR slot assignment
// makes the staging-write side uniform over the 8 four-bank groups.
// Split-K: qt>=17 split into two key-range halves on separate blocks
// (critical path 32 -> 17 tiles); last-arriver merges via atomic flag.
__global__ __launch_bounds__(256) void flash_attn(const bf16* __restrict__ Q,
                                                  const bf16* __restrict__ Kg,
                                                  const bf16* __restrict__ Vtg,
                                                  bf16* __restrict__ O,
                                                  float* __restrict__ PO,
                                                  float* __restrict__ Pm,
                                                  float* __restrict__ Pl,
                                                  unsigned* __restrict__ Pf) {
  constexpr int D = 1024, S = 2048;
  const float MASK = -3.0e4f;
  const float SCL2 = 0.18033688011112042f;  // log2(e)/sqrt(64)
  __shared__ bf16 Ks[4096];  // 8KB fragment-major [nt][kc][quad][la^]
  __shared__ bf16 Vs[4096];  // 8KB fragment-major
  __shared__ bf16 Ps[4096];  // 4 waves x 2KB fragment-major
  __shared__ int roleShare;

  int n = blockIdx.x;
  int bh = n & 31;
  int it = n >> 5;  // 0..46, big-first
  int qt, t0, t1, pa_ = 0;
  bool split;
  if (it < 30) {
    pa_ = it >> 1;
    int half = it & 1;
    qt = 31 - pa_;  // 31..17
    int hsp = (qt + 1) >> 1;
    split = true;
    t0 = half ? hsp : 0;
    t1 = half ? qt + 1 : hsp;
  } else {
    qt = 46 - it;  // 16..0
    split = false;
    t0 = 0;
    t1 = qt + 1;
  }
  int b = bh >> 4, h = bh & 15;
  int tid = threadIdx.x, wave = tid >> 6, lane = tid & 63;
  int la = lane & 15, quad = lane >> 4;
  const size_t base = (size_t)b * S * D + (size_t)h * 64;
  const bf16* Qg = Q + base;
  const bf16* Kb = Kg + base;
  const bf16* Vb = Vtg + (size_t)bh * 64 * S;  // [hd][s]
  int r0 = tid >> 3, c0 = (tid & 7) * 8;  // staging: rows r0,r0+32; col chunk c0

  // LDS element offsets (fragment-major)
  int quads = (tid & 7) & 3, kcs = (tid & 7) >> 2;
  int st0 = (r0 >> 4) * 1024 + kcs * 512 + quads * 128 +
            (((r0 & 15) ^ quads ^ (kcs << 2)) * 8);          // staging write (r0); +2048 for r0+32
  int kvrd0 = quad * 128 + ((la ^ quad) * 8);                // K/V frag read, kc=0 (+ nt*1024)
  int kvrd1 = 512 + quad * 128 + ((la ^ quad ^ 4) * 8);      // kc=1
  int prd0 = wave * 1024 + quad * 128 + ((la ^ ((quad & 1) << 2)) * 8);  // P read kc=0
  int prd1 = prd0 + 512;
  int pwb = wave * 1024 + (quad >> 1) * 128 +
            ((la ^ ((quad >> 1) << 2)) * 8) + (quad & 1) * 4;  // P write (+ nt*256)

  f32x4 zero = {0.f, 0.f, 0.f, 0.f};
  int q0 = qt * 64;

  // Q B-frags (pre-scaled by SCL2): lane la holds Q[q0+wave*16+la][quad*8+j]
  bf16x8 aq[2];
  {
    int qrow = q0 + wave * 16 + la;
#pragma unroll
    for (int kc = 0; kc < 2; ++kc) {
      bf16x8 t = *(const bf16x8*)&Qg[(size_t)qrow * D + kc * 32 + quad * 8];
#pragma unroll
      for (int i = 0; i < 8; ++i) t[i] = (bf16)((float)t[i] * SCL2);
      aq[kc] = t;
    }
  }

  f32x4 o[4];
#pragma unroll
  for (int nt = 0; nt < 4; ++nt) o[nt] = zero;
  float m_l = MASK, l_l = 0.f;

  // prefetch tile t0
  int kb0 = t0 * 64;
  bf16x8 kr0 = *(const bf16x8*)&Kb[(size_t)(kb0 + r0) * D + c0];
  bf16x8 kr1 = *(const bf16x8*)&Kb[(size_t)(kb0 + r0 + 32) * D + c0];
  bf16x8 vr0 = *(const bf16x8*)&Vb[(size_t)r0 * S + kb0 + c0];
  bf16x8 vr1 = *(const bf16x8*)&Vb[(size_t)(r0 + 32) * S + kb0 + c0];

  for (int t = t0; t < t1; ++t) {
    *(bf16x8*)&Ks[st0] = kr0;
    *(bf16x8*)&Ks[st0 + 2048] = kr1;
    *(bf16x8*)&Vs[st0] = vr0;
    *(bf16x8*)&Vs[st0 + 2048] = vr1;
    __syncthreads();
    if (t + 1 < t1) {  // prefetch next tile (latency hidden behind compute)
      int kb2 = (t + 1) * 64;
      kr0 = *(const bf16x8*)&Kb[(size_t)(kb2 + r0) * D + c0];
      kr1 = *(const bf16x8*)&Kb[(size_t)(kb2 + r0 + 32) * D + c0];
      vr0 = *(const bf16x8*)&Vb[(size_t)r0 * S + kb2 + c0];
      vr1 = *(const bf16x8*)&Vb[(size_t)(r0 + 32) * S + kb2 + c0];
    }

    // S^T = K @ Q^T : lane holds S[q=la][key = t*64 + nt*16 + quad*4 + r]
    f32x4 s[4];
    __builtin_amdgcn_s_setprio(1);
#pragma unroll
    for (int nt = 0; nt < 4; ++nt) {
      bf16x8 k0f = *(const bf16x8*)&Ks[nt * 1024 + kvrd0];
      bf16x8 k1f = *(const bf16x8*)&Ks[nt * 1024 + kvrd1];
      f32x4 z = zero;
      z = MFMA16(k0f, aq[0], z);
      z = MFMA16(k1f, aq[1], z);
      s[nt] = z;
    }
    __builtin_amdgcn_s_setprio(0);

    // mask only the diagonal tile
    if (t == qt) {
      int qa = q0 + wave * 16 + la;
      int kb = t * 64;
#pragma unroll
      for (int nt = 0; nt < 4; ++nt)
#pragma unroll
        for (int r = 0; r < 4; ++r) {
          int ka = kb + nt * 16 + quad * 4 + r;
          s[nt][r] = (ka > qa) ? MASK : s[nt][r];
        }
    }

    // online softmax: tree max in-lane over 16 keys, then cross-quad butterfly
    float mx;
    {
      float u0 = fmaxf(fmaxf(s[0][0], s[0][1]), fmaxf(s[0][2], s[0][3]));
      float u1 = fmaxf(fmaxf(s[1][0], s[1][1]), fmaxf(s[1][2], s[1][3]));
      float u2 = fmaxf(fmaxf(s[2][0], s[2][1]), fmaxf(s[2][2], s[2][3]));
      float u3 = fmaxf(fmaxf(s[3][0], s[3][1]), fmaxf(s[3][2], s[3][3]));
      mx = fmaxf(fmaxf(u0, u1), fmaxf(u2, u3));
    }
    mx = fmaxf(mx, m_l);
    mx = fmaxf(mx, __shfl_xor(mx, 16, 64));
    mx = fmaxf(mx, __shfl_xor(mx, 32, 64));

    // defer-max: only rescale when some row's max grew past THR (log2 domain)
    if (!__all(mx - m_l <= 8.0f)) {
      float alpha = __builtin_amdgcn_exp2f(m_l - mx);
      m_l = mx;
      l_l *= alpha;
      float ab[4];
#pragma unroll
      for (int r = 0; r < 4; ++r) ab[r] = __shfl(alpha, quad * 4 + r, 64);
#pragma unroll
      for (int nt = 0; nt < 4; ++nt)
#pragma unroll
        for (int r = 0; r < 4; ++r) o[nt][r] *= ab[r];
    }

    float rs = 0.f;
#pragma unroll
    for (int nt = 0; nt < 4; ++nt) {
      float p0 = __builtin_amdgcn_exp2f(s[nt][0] - m_l);
      float p1 = __builtin_amdgcn_exp2f(s[nt][1] - m_l);
      float p2 = __builtin_amdgcn_exp2f(s[nt][2] - m_l);
      float p3 = __builtin_amdgcn_exp2f(s[nt][3] - m_l);
      s[nt][0] = p0; s[nt][1] = p1; s[nt][2] = p2; s[nt][3] = p3;
      rs += (p0 + p1) + (p2 + p3);
    }
    rs += __shfl_xor(rs, 16, 64);
    rs += __shfl_xor(rs, 32, 64);
    l_l += rs;

    // spill P (wave-private fragment-major; in-wave LDS order + waitcnt safe)
#pragma unroll
    for (int nt = 0; nt < 4; ++nt) {
      bf16x4 pk;
#pragma unroll
      for (int r = 0; r < 4; ++r) pk[r] = (bf16)s[nt][r];
      *(bf16x4*)&Ps[pwb + nt * 256] = pk;
    }

    // O += P @ V
    __builtin_amdgcn_s_setprio(1);
    {
      bf16x8 ap0 = *(const bf16x8*)&Ps[prd0];
#pragma unroll
      for (int nt = 0; nt < 4; ++nt) {
        bf16x8 bv = *(const bf16x8*)&Vs[nt * 1024 + kvrd0];
        o[nt] = MFMA16(ap0, bv, o[nt]);
      }
      bf16x8 ap1 = *(const bf16x8*)&Ps[prd1];
#pragma unroll
      for (int nt = 0; nt < 4; ++nt) {
        bf16x8 bv = *(const bf16x8*)&Vs[nt * 1024 + kvrd1];
        o[nt] = MFMA16(ap1, bv, o[nt]);
      }
    }
    __builtin_amdgcn_s_setprio(0);
    __syncthreads();  // protect Ks/Vs for next tile
  }

  if (!split) {
    // epilogue: l lives at lane la==row; broadcast, normalize, store
    float inv[4];
#pragma unroll
    for (int r = 0; r < 4; ++r) {
      float lv = __shfl(l_l, quad * 4 + r, 64);
      inv[r] = (lv > 1e-30f) ? 1.0f / lv : 0.0f;
    }
#pragma unroll
    for (int nt = 0; nt < 4; ++nt) {
      int hd = nt * 16 + la;
#pragma unroll
      for (int r = 0; r < 4; ++r) {
        int row = q0 + wave * 16 + quad * 4 + r;
        O[base + (size_t)row * D + hd] = (bf16)(o[nt][r] * inv[r]);
      }
    }
    return;
  }

  // ---- split-tile epilogue: last-arriver merges ----
  int pidx = pa_ * 32 + bh;
  float* myO = PO + (size_t)pidx * 4096;
  if (tid == 0)
    roleShare = (int)__hip_atomic_fetch_add(&Pf[pidx], 1u, __ATOMIC_ACQ_REL,
                                            __HIP_MEMORY_SCOPE_AGENT);
  __syncthreads();
  int role = roleShare;
  if (role == 0) {
    // first finisher: publish unnormalized partial (f32) + per-row m,l
#pragma unroll
    for (int nt = 0; nt < 4; ++nt)
#pragma unroll
      for (int r = 0; r < 4; ++r)
        myO[(wave * 16 + quad * 4 + r) * 64 + nt * 16 + la] = o[nt][r];
    if (quad == 0) {
      Pm[pidx * 64 + wave * 16 + la] = m_l;
      Pl[pidx * 64 + wave * 16 + la] = l_l;
    }
    __threadfence();
    __syncthreads();
    if (tid == 0)
      __hip_atomic_fetch_add(&Pf[pidx], 1u, __ATOMIC_RELEASE, __HIP_MEMORY_SCOPE_AGENT);
    return;
  }
  if (role == 1) {
    // writer claimed but not yet published: bounded spin (producer is resident & running)
    if (tid == 0) {
      while (__hip_atomic_load(&Pf[pidx], __ATOMIC_ACQUIRE, __HIP_MEMORY_SCOPE_AGENT) < 3u) {}
    }
    __syncthreads();
  }
  __threadfence();
  float m2 = Pm[pidx * 64 + wave * 16 + la];
  float l2 = Pl[pidx * 64 + wave * 16 + la];
  float mM = fmaxf(m_l, m2);
  float a1 = __builtin_amdgcn_exp2f(m_l - mM);
  float a2 = __builtin_amdgcn_exp2f(m2 - mM);
  float lM = l_l * a1 + l2 * a2;
  float linv = (lM > 1e-30f) ? 1.0f / lM : 0.0f;
  float a1b[4], a2b[4], ivb[4];
#pragma unroll
  for (int r = 0; r < 4; ++r) {
    a1b[r] = __shfl(a1, quad * 4 + r, 64);
    a2b[r] = __shfl(a2, quad * 4 + r, 64);
    ivb[r] = __shfl(linv, quad * 4 + r, 64);
  }
#pragma unroll
  for (int nt = 0; nt < 4; ++nt) {
    int hd = nt * 16 + la;
#pragma unroll
    for (int r = 0; r < 4; ++r) {
      float o2 = myO[(wave * 16 + quad * 4 + r) * 64 + hd];
      int row = q0 + wave * 16 + quad * 4 + r;
      O[base + (size_t)row * D + hd] = (bf16)((o[nt][r] * a1b[r] + o2 * a2b[r]) * ivb[r]);
    }
  }
}

extern "C" void kernel_launch(void* const* d_in, const int* in_sizes, int n_in,
                              void* d_out, int out_size, void* d_ws, size_t ws_size,
                              hipStream_t stream) {
  constexpr int B = 2, S = 2048, D = 1024;
  constexpr int M = B * S;
  constexpr size_t WN = (size_t)D * D;
  constexpr size_t XN = (size_t)M * D;

  const float* x = (const float*)d_in[0];
  const float* Wq = (const float*)d_in[1];
  const float* Wk = (const float*)d_in[2];
  const float* Wv = (const float*)d_in[3];
  const float* Wo = (const float*)d_in[4];
  float* out = (float*)d_out;

  if (ws_size < 2 * XN * sizeof(bf16)) return;
  bf16* Qb = (bf16*)d_ws;   // [0,8MB): Q, then O (flash aliases)
  bf16* Vtg = Qb + XN;      // [8,16MB): V^T [bh][hd][s]
  bf16* Wt = Vtg + XN;      // [16,24MB): 4x W^T bf16 (if ws allows)
  bf16* Kb = (bf16*)d_out;  // d_out[0,8MB): K (scratch until final gemm)
  bf16* Vb = Kb + XN;       // d_out[8,16MB): V (dead after vtrans); then partials
  bool use_bt = ws_size >= (2 * XN + 4 * WN) * sizeof(bf16);

  // split-K partials live in d_out[8MB..): free after vtrans, dead before final gemm
  char* pbase = (char*)d_out + XN * sizeof(bf16);
  float* PO = (float*)pbase;            // 480 tiles x 64x64 f32 = 7.50 MB
  float* Pm = PO + 480 * 4096;          // 480 x 64 f32
  float* Pl = Pm + 480 * 64;            // 480 x 64 f32
  unsigned* Pf = (unsigned*)(Pl + 480 * 64);  // 480 flags

  dim3 gq(M / 128, 24), gf(M / 128, 8);
  if (use_bt) {
    prep_wt<<<dim3(32, 32, 4), 256, 0, stream>>>(Wq, Wk, Wv, Wo, Wt, D);
    gemm3<float, bf16, true><<<gq, 256, 0, stream>>>(x, Wt, Wt + WN, Wt + 2 * WN,
                                                     Qb, Kb, Vb, M, D, D, 8);
  } else {
    gemm3<float, bf16, false><<<gq, 256, 0, stream>>>(x, Wq, Wk, Wv, Qb, Kb, Vb, M, D, D, 8);
  }
  vtrans<<<dim3(S / 32, 2, 32), 256, 0, stream>>>(Vb, Vtg);
  hipMemsetAsync(Pf, 0, 480 * sizeof(unsigned), stream);
  flash_attn<<<dim3(1504), 256, 0, stream>>>(Qb, Kb, Vtg, Qb, PO, Pm, Pl, Pf);
  if (use_bt) {
    gemm3<bf16, float, true><<<gf, 256, 0, stream>>>(Qb, Wt + 3 * WN, Wt + 3 * WN, Wt + 3 * WN,
                                                     out, out, out, M, D, D, 8);
  } else {
    gemm3<bf16, float, false><<<gf, 256, 0, stream>>>(Qb, Wo, Wo, Wo, out, out, out, M, D, D, 8);
  }
}

// Round 3
// 178.089 us; speedup vs baseline: 1.9742x; 1.9742x over previous
//
#include <hip/hip_runtime.h>
#include <hip/hip_bf16.h>
#include <cstdint>

typedef __bf16 bf16;
typedef bf16 bf16x8 __attribute__((ext_vector_type(8)));
typedef bf16 bf16x4 __attribute__((ext_vector_type(4)));
typedef float f32x4 __attribute__((ext_vector_type(4)));

#define MFMA16(a, b, c) __builtin_amdgcn_mfma_f32_16x16x32_bf16(a, b, c, 0, 0, 0)

struct rawF { f32x4 a, b; };
__device__ inline rawF ldr(const float* p) {
  rawF r; r.a = *(const f32x4*)p; r.b = *(const f32x4*)(p + 4); return r;
}
__device__ inline bf16x8 ldr(const bf16* p) { return *(const bf16x8*)p; }
__device__ inline bf16x8 cv(const rawF& r) {
  bf16x8 o;
#pragma unroll
  for (int i = 0; i < 4; ++i) { o[i] = (bf16)r.a[i]; o[i + 4] = (bf16)r.b[i]; }
  return o;
}
__device__ inline bf16x8 cv(const bf16x8& r) { return r; }
__device__ inline void stC(bf16* C, size_t i, float v) { C[i] = (bf16)v; }
__device__ inline void stC(float* C, size_t i, float v) { C[i] = v; }

// ---- prep: transpose-convert 4 weights fp32 [K][N] -> bf16 [N][K] ----
__global__ __launch_bounds__(256) void prep_wt(const float* __restrict__ W0,
                                               const float* __restrict__ W1,
                                               const float* __restrict__ W2,
                                               const float* __restrict__ W3,
                                               bf16* __restrict__ Wt, int n) {
  const float* Ws[4] = {W0, W1, W2, W3};
  const float* W = Ws[blockIdx.z];
  bf16* out = Wt + (size_t)blockIdx.z * n * n;
  __shared__ bf16 t[32][33];
  int bx = blockIdx.x * 32, by = blockIdx.y * 32;
  int tx = threadIdx.x & 31, ty = threadIdx.x >> 5;
#pragma unroll
  for (int i = 0; i < 32; i += 8)
    t[ty + i][tx] = (bf16)W[(size_t)(by + ty + i) * n + bx + tx];
  __syncthreads();
#pragma unroll
  for (int i = 0; i < 32; i += 8)
    out[(size_t)(bx + ty + i) * n + by + tx] = t[tx][ty + i];
}

// ---- transpose V bf16 [b*s][D] -> Vt [bh][hd][2048] ----
__global__ __launch_bounds__(256) void vtrans(const bf16* __restrict__ V, bf16* __restrict__ Vt) {
  constexpr int Sn = 2048, Dn = 1024;
  __shared__ bf16 t[32][33];
  int s0 = blockIdx.x * 32, hd0 = blockIdx.y * 32, bh = blockIdx.z;
  int b = bh >> 4, h = bh & 15;
  int tx = threadIdx.x & 31, ty = threadIdx.x >> 5;
#pragma unroll
  for (int i = 0; i < 32; i += 8)
    t[ty + i][tx] = V[(size_t)(b * Sn + s0 + ty + i) * Dn + h * 64 + hd0 + tx];
  __syncthreads();
#pragma unroll
  for (int i = 0; i < 32; i += 8)
    Vt[(size_t)bh * 64 * Sn + (size_t)(hd0 + ty + i) * Sn + s0 + tx] = t[tx][ty + i];
}

// ---- GEMM C[M,N] = A[M,K] @ B; register-prefetched k-loop; 3 outputs via blockIdx.y ----
template <typename TA, typename TC, bool BT>
__global__ __launch_bounds__(256) void gemm3(const TA* __restrict__ A,
                                             const void* __restrict__ B0p,
                                             const void* __restrict__ B1p,
                                             const void* __restrict__ B2p,
                                             TC* __restrict__ C0, TC* __restrict__ C1,
                                             TC* __restrict__ C2, int M, int N, int K, int nblk) {
  constexpr int LDA = 40;
  constexpr int LDB = BT ? 40 : 32;
  __shared__ bf16 As[128 * LDA];
  __shared__ bf16 Bs[128 * LDB];
  int tid = threadIdx.x, wave = tid >> 6, lane = tid & 63;
  int la = lane & 15, quad = lane >> 4;
  int wr = (wave >> 1) * 64, wc = (wave & 1) * 64;
  int by = blockIdx.y;
  int sel = by / nblk;
  int n0 = (by - sel * nblk) * 128;
  const void* Bp = sel == 0 ? B0p : (sel == 1 ? B1p : B2p);
  TC* C = sel == 0 ? C0 : (sel == 1 ? C1 : C2);
  const TA* Ab = A + (size_t)blockIdx.x * 128 * K;
  using TB = typename std::conditional<BT, bf16, float>::type;
  const TB* Bm = (const TB*)Bp;

  // per-p staging indices
  int ar[2], ac[2], br[2], bc[2];
#pragma unroll
  for (int p = 0; p < 2; ++p) {
    int li = (tid + p * 256) * 8;
    ar[p] = li >> 5; ac[p] = li & 31;       // A: row, kcol
    if (BT) { br[p] = li >> 5; bc[p] = li & 31; }    // B^T: nrow, kcol
    else    { br[p] = li >> 7; bc[p] = li & 127; }   // B: krow, ncol
  }

  f32x4 zero = {0.f, 0.f, 0.f, 0.f};
  f32x4 acc[4][4];
#pragma unroll
  for (int i = 0; i < 4; ++i)
#pragma unroll
    for (int j = 0; j < 4; ++j) acc[i][j] = zero;

  decltype(ldr((const TA*)nullptr)) pa[2];
  decltype(ldr((const TB*)nullptr)) pb[2];
#pragma unroll
  for (int p = 0; p < 2; ++p) {
    pa[p] = ldr(&Ab[(size_t)ar[p] * K + ac[p]]);
    if (BT) pb[p] = ldr(&Bm[(size_t)(n0 + br[p]) * K + bc[p]]);
    else    pb[p] = ldr(&Bm[(size_t)br[p] * N + n0 + bc[p]]);
  }

  for (int k0 = 0; k0 < K; k0 += 32) {
#pragma unroll
    for (int p = 0; p < 2; ++p) {
      *(bf16x8*)&As[ar[p] * LDA + ac[p]] = cv(pa[p]);
      if constexpr (BT) {
        *(bf16x8*)&Bs[br[p] * LDB + bc[p]] = cv(pb[p]);
      } else {
        bf16x8 v = cv(pb[p]);
        int kx = br[p] ^ (((bc[p] >> 3) & 3) << 3);
#pragma unroll
        for (int j = 0; j < 8; ++j) Bs[(bc[p] + j) * 32 + kx] = v[j];
      }
    }
    __syncthreads();
    int k1 = k0 + 32;
    if (k1 < K) {
#pragma unroll
      for (int p = 0; p < 2; ++p) {
        pa[p] = ldr(&Ab[(size_t)ar[p] * K + k1 + ac[p]]);
        if (BT) pb[p] = ldr(&Bm[(size_t)(n0 + br[p]) * K + k1 + bc[p]]);
        else    pb[p] = ldr(&Bm[(size_t)(k1 + br[p]) * N + n0 + bc[p]]);
      }
    }
    bf16x8 af[4], bfr[4];
#pragma unroll
    for (int i = 0; i < 4; ++i)
      af[i] = *(const bf16x8*)&As[(wr + i * 16 + la) * LDA + quad * 8];
#pragma unroll
    for (int j = 0; j < 4; ++j) {
      int nr = wc + j * 16 + la;
      if constexpr (BT)
        bfr[j] = *(const bf16x8*)&Bs[nr * LDB + quad * 8];
      else
        bfr[j] = *(const bf16x8*)&Bs[nr * 32 + ((quad * 8) ^ (((nr >> 3) & 3) << 3))];
    }
#pragma unroll
    for (int i = 0; i < 4; ++i)
#pragma unroll
      for (int j = 0; j < 4; ++j) acc[i][j] = MFMA16(af[i], bfr[j], acc[i][j]);
    __syncthreads();
  }
#pragma unroll
  for (int i = 0; i < 4; ++i) {
#pragma unroll
    for (int j = 0; j < 4; ++j) {
      int col = n0 + wc + j * 16 + la;
#pragma unroll
      for (int r = 0; r < 4; ++r) {
        int row = blockIdx.x * 128 + wr + i * 16 + quad * 4 + r;
        stC(C, (size_t)row * N + col, acc[i][j][r]);
      }
    }
  }
}

// ---- flash attention, causal, HD=64; transposed scores (S^T = K@Q^T) ----
// grid (1024): one 64-row q-tile per block, big-tiles-first bijective mapping;
// blocks {n, n+256, n+512, n+768} have qts summing to 62 (CU-balanced) and
// share bh within each 32-block run (K/V L2 locality). All 1024 blocks fit
// co-resident (24KB LDS -> 6 blocks/CU), so dispatch order is non-critical.
// Fragment-major LDS: each MFMA fragment read covers one contiguous 1024B
// block (zero read conflicts); XOR slot assignment balances staging writes.
// [round 2 measured: conflicts 5.95M -> 1.62M with this layout]
__global__ __launch_bounds__(256) void flash_attn(const bf16* __restrict__ Q,
                                                  const bf16* __restrict__ Kg,
                                                  const bf16* __restrict__ Vtg,
                                                  bf16* __restrict__ O) {
  constexpr int D = 1024, S = 2048;
  const float MASK = -3.0e4f;
  const float SCL2 = 0.18033688011112042f;  // log2(e)/sqrt(64)
  __shared__ bf16 Ks[4096];  // 8KB fragment-major [nt][kc][quad][la^]
  __shared__ bf16 Vs[4096];  // 8KB fragment-major
  __shared__ bf16 Ps[4096];  // 4 waves x 2KB fragment-major

  int n = blockIdx.x;
  int bh = n & 31;
  int j5 = n >> 5;                        // 0..31
  int j = j5 & 15;
  int qt = (j5 & 16) ? j : 31 - j;        // big-first, bijective, CU-balanced
  int b = bh >> 4, h = bh & 15;
  int tid = threadIdx.x, wave = tid >> 6, lane = tid & 63;
  int la = lane & 15, quad = lane >> 4;
  const size_t base = (size_t)b * S * D + (size_t)h * 64;
  const bf16* Qg = Q + base;
  const bf16* Kb = Kg + base;
  const bf16* Vb = Vtg + (size_t)bh * 64 * S;  // [hd][s]
  int r0 = tid >> 3, c0 = (tid & 7) * 8;  // staging: rows r0,r0+32; col chunk c0

  // LDS element offsets (fragment-major)
  int quads = (tid & 7) & 3, kcs = (tid & 7) >> 2;
  int st0 = (r0 >> 4) * 1024 + kcs * 512 + quads * 128 +
            (((r0 & 15) ^ quads ^ (kcs << 2)) * 8);          // staging write (r0); +2048 for r0+32
  int kvrd0 = quad * 128 + ((la ^ quad) * 8);                // K/V frag read, kc=0 (+ nt*1024)
  int kvrd1 = 512 + quad * 128 + ((la ^ quad ^ 4) * 8);      // kc=1
  int prd0 = wave * 1024 + quad * 128 + ((la ^ ((quad & 1) << 2)) * 8);  // P read kc=0
  int prd1 = prd0 + 512;
  int pwb = wave * 1024 + (quad >> 1) * 128 +
            ((la ^ ((quad >> 1) << 2)) * 8) + (quad & 1) * 4;  // P write (+ nt*256)

  f32x4 zero = {0.f, 0.f, 0.f, 0.f};
  int q0 = qt * 64;
  int ntiles = qt + 1;

  // Q B-frags (pre-scaled by SCL2): lane la holds Q[q0+wave*16+la][quad*8+j]
  bf16x8 aq[2];
  {
    int qrow = q0 + wave * 16 + la;
#pragma unroll
    for (int kc = 0; kc < 2; ++kc) {
      bf16x8 t = *(const bf16x8*)&Qg[(size_t)qrow * D + kc * 32 + quad * 8];
#pragma unroll
      for (int i = 0; i < 8; ++i) t[i] = (bf16)((float)t[i] * SCL2);
      aq[kc] = t;
    }
  }

  f32x4 o[4];
#pragma unroll
  for (int nt = 0; nt < 4; ++nt) o[nt] = zero;
  float m_l = MASK, l_l = 0.f;

  // prefetch tile 0
  bf16x8 kr0 = *(const bf16x8*)&Kb[(size_t)r0 * D + c0];
  bf16x8 kr1 = *(const bf16x8*)&Kb[(size_t)(r0 + 32) * D + c0];
  bf16x8 vr0 = *(const bf16x8*)&Vb[(size_t)r0 * S + c0];
  bf16x8 vr1 = *(const bf16x8*)&Vb[(size_t)(r0 + 32) * S + c0];

  for (int t = 0; t < ntiles; ++t) {
    *(bf16x8*)&Ks[st0] = kr0;
    *(bf16x8*)&Ks[st0 + 2048] = kr1;
    *(bf16x8*)&Vs[st0] = vr0;
    *(bf16x8*)&Vs[st0 + 2048] = vr1;
    __syncthreads();
    if (t + 1 < ntiles) {  // prefetch next tile (latency hidden behind compute)
      int kb2 = (t + 1) * 64;
      kr0 = *(const bf16x8*)&Kb[(size_t)(kb2 + r0) * D + c0];
      kr1 = *(const bf16x8*)&Kb[(size_t)(kb2 + r0 + 32) * D + c0];
      vr0 = *(const bf16x8*)&Vb[(size_t)r0 * S + kb2 + c0];
      vr1 = *(const bf16x8*)&Vb[(size_t)(r0 + 32) * S + kb2 + c0];
    }

    // S^T = K @ Q^T : lane holds S[q=la][key = t*64 + nt*16 + quad*4 + r]
    f32x4 s[4];
    __builtin_amdgcn_s_setprio(1);
#pragma unroll
    for (int nt = 0; nt < 4; ++nt) {
      bf16x8 k0f = *(const bf16x8*)&Ks[nt * 1024 + kvrd0];
      bf16x8 k1f = *(const bf16x8*)&Ks[nt * 1024 + kvrd1];
      f32x4 z = zero;
      z = MFMA16(k0f, aq[0], z);
      z = MFMA16(k1f, aq[1], z);
      s[nt] = z;
    }
    __builtin_amdgcn_s_setprio(0);

    // mask only the diagonal tile
    if (t == qt) {
      int qa = q0 + wave * 16 + la;
      int kb = t * 64;
#pragma unroll
      for (int nt = 0; nt < 4; ++nt)
#pragma unroll
        for (int r = 0; r < 4; ++r) {
          int ka = kb + nt * 16 + quad * 4 + r;
          s[nt][r] = (ka > qa) ? MASK : s[nt][r];
        }
    }

    // online softmax: tree max in-lane over 16 keys, then cross-quad butterfly
    float mx;
    {
      float u0 = fmaxf(fmaxf(s[0][0], s[0][1]), fmaxf(s[0][2], s[0][3]));
      float u1 = fmaxf(fmaxf(s[1][0], s[1][1]), fmaxf(s[1][2], s[1][3]));
      float u2 = fmaxf(fmaxf(s[2][0], s[2][1]), fmaxf(s[2][2], s[2][3]));
      float u3 = fmaxf(fmaxf(s[3][0], s[3][1]), fmaxf(s[3][2], s[3][3]));
      mx = fmaxf(fmaxf(u0, u1), fmaxf(u2, u3));
    }
    mx = fmaxf(mx, m_l);
    mx = fmaxf(mx, __shfl_xor(mx, 16, 64));
    mx = fmaxf(mx, __shfl_xor(mx, 32, 64));

    // defer-max: only rescale when some row's max grew past THR (log2 domain)
    if (!__all(mx - m_l <= 8.0f)) {
      float alpha = __builtin_amdgcn_exp2f(m_l - mx);
      m_l = mx;
      l_l *= alpha;
      float ab[4];
#pragma unroll
      for (int r = 0; r < 4; ++r) ab[r] = __shfl(alpha, quad * 4 + r, 64);
#pragma unroll
      for (int nt = 0; nt < 4; ++nt)
#pragma unroll
        for (int r = 0; r < 4; ++r) o[nt][r] *= ab[r];
    }

    float rs = 0.f;
#pragma unroll
    for (int nt = 0; nt < 4; ++nt) {
      float p0 = __builtin_amdgcn_exp2f(s[nt][0] - m_l);
      float p1 = __builtin_amdgcn_exp2f(s[nt][1] - m_l);
      float p2 = __builtin_amdgcn_exp2f(s[nt][2] - m_l);
      float p3 = __builtin_amdgcn_exp2f(s[nt][3] - m_l);
      s[nt][0] = p0; s[nt][1] = p1; s[nt][2] = p2; s[nt][3] = p3;
      rs += (p0 + p1) + (p2 + p3);
    }
    rs += __shfl_xor(rs, 16, 64);
    rs += __shfl_xor(rs, 32, 64);
    l_l += rs;

    // spill P (wave-private fragment-major; in-wave LDS order + waitcnt safe)
#pragma unroll
    for (int nt = 0; nt < 4; ++nt) {
      bf16x4 pk;
#pragma unroll
      for (int r = 0; r < 4; ++r) pk[r] = (bf16)s[nt][r];
      *(bf16x4*)&Ps[pwb + nt * 256] = pk;
    }

    // O += P @ V
    __builtin_amdgcn_s_setprio(1);
    {
      bf16x8 ap0 = *(const bf16x8*)&Ps[prd0];
#pragma unroll
      for (int nt = 0; nt < 4; ++nt) {
        bf16x8 bv = *(const bf16x8*)&Vs[nt * 1024 + kvrd0];
        o[nt] = MFMA16(ap0, bv, o[nt]);
      }
      bf16x8 ap1 = *(const bf16x8*)&Ps[prd1];
#pragma unroll
      for (int nt = 0; nt < 4; ++nt) {
        bf16x8 bv = *(const bf16x8*)&Vs[nt * 1024 + kvrd1];
        o[nt] = MFMA16(ap1, bv, o[nt]);
      }
    }
    __builtin_amdgcn_s_setprio(0);
    __syncthreads();  // protect Ks/Vs for next tile
  }

  // epilogue: l lives at lane la==row; broadcast, normalize, store
  float inv[4];
#pragma unroll
  for (int r = 0; r < 4; ++r) {
    float lv = __shfl(l_l, quad * 4 + r, 64);
    inv[r] = (lv > 1e-30f) ? 1.0f / lv : 0.0f;
  }
#pragma unroll
  for (int nt = 0; nt < 4; ++nt) {
    int hd = nt * 16 + la;
#pragma unroll
    for (int r = 0; r < 4; ++r) {
      int row = q0 + wave * 16 + quad * 4 + r;
      O[base + (size_t)row * D + hd] = (bf16)(o[nt][r] * inv[r]);
    }
  }
}

extern "C" void kernel_launch(void* const* d_in, const int* in_sizes, int n_in,
                              void* d_out, int out_size, void* d_ws, size_t ws_size,
                              hipStream_t stream) {
  constexpr int B = 2, S = 2048, D = 1024;
  constexpr int M = B * S;
  constexpr size_t WN = (size_t)D * D;
  constexpr size_t XN = (size_t)M * D;

  const float* x = (const float*)d_in[0];
  const float* Wq = (const float*)d_in[1];
  const float* Wk = (const float*)d_in[2];
  const float* Wv = (const float*)d_in[3];
  const float* Wo = (const float*)d_in[4];
  float* out = (float*)d_out;

  if (ws_size < 2 * XN * sizeof(bf16)) return;
  bf16* Qb = (bf16*)d_ws;   // [0,8MB): Q, then O (flash aliases)
  bf16* Vtg = Qb + XN;      // [8,16MB): V^T [bh][hd][s]
  bf16* Wt = Vtg + XN;      // [16,24MB): 4x W^T bf16 (if ws allows)
  bf16* Kb = (bf16*)d_out;  // d_out[0,8MB): K (scratch until final gemm)
  bf16* Vb = Kb + XN;       // d_out[8,16MB): V (dead after vtrans)
  bool use_bt = ws_size >= (2 * XN + 4 * WN) * sizeof(bf16);

  dim3 gq(M / 128, 24), gf(M / 128, 8);
  if (use_bt) {
    prep_wt<<<dim3(32, 32, 4), 256, 0, stream>>>(Wq, Wk, Wv, Wo, Wt, D);
    gemm3<float, bf16, true><<<gq, 256, 0, stream>>>(x, Wt, Wt + WN, Wt + 2 * WN,
                                                     Qb, Kb, Vb, M, D, D, 8);
  } else {
    gemm3<float, bf16, false><<<gq, 256, 0, stream>>>(x, Wq, Wk, Wv, Qb, Kb, Vb, M, D, D, 8);
  }
  vtrans<<<dim3(S / 32, 2, 32), 256, 0, stream>>>(Vb, Vtg);
  flash_attn<<<dim3(1024), 256, 0, stream>>>(Qb, Kb, Vtg, Qb);
  if (use_bt) {
    gemm3<bf16, float, true><<<gf, 256, 0, stream>>>(Qb, Wt + 3 * WN, Wt + 3 * WN, Wt + 3 * WN,
                                                     out, out, out, M, D, D, 8);
  } else {
    gemm3<bf16, float, false><<<gf, 256, 0, stream>>>(Qb, Wo, Wo, Wo, out, out, out, M, D, D, 8);
  }
}

// Round 4
// 176.362 us; speedup vs baseline: 1.9935x; 1.0098x over previous
//
#include <hip/hip_runtime.h>
#include <hip/hip_bf16.h>
#include <cstdint>

typedef __bf16 bf16;
typedef bf16 bf16x8 __attribute__((ext_vector_type(8)));
typedef bf16 bf16x4 __attribute__((ext_vector_type(4)));
typedef float f32x4 __attribute__((ext_vector_type(4)));

#define MFMA16(a, b, c) __builtin_amdgcn_mfma_f32_16x16x32_bf16(a, b, c, 0, 0, 0)

struct rawF { f32x4 a, b; };
__device__ inline rawF ldr(const float* p) {
  rawF r; r.a = *(const f32x4*)p; r.b = *(const f32x4*)(p + 4); return r;
}
__device__ inline bf16x8 ldr(const bf16* p) { return *(const bf16x8*)p; }
__device__ inline bf16x8 cv(const rawF& r) {
  bf16x8 o;
#pragma unroll
  for (int i = 0; i < 4; ++i) { o[i] = (bf16)r.a[i]; o[i + 4] = (bf16)r.b[i]; }
  return o;
}
__device__ inline bf16x8 cv(const bf16x8& r) { return r; }
__device__ inline void stC(bf16* C, size_t i, float v) { C[i] = (bf16)v; }
__device__ inline void stC(float* C, size_t i, float v) { C[i] = v; }

// ---- prep: transpose-convert 4 weights fp32 [K][N] -> bf16 [N][K] ----
__global__ __launch_bounds__(256) void prep_wt(const float* __restrict__ W0,
                                               const float* __restrict__ W1,
                                               const float* __restrict__ W2,
                                               const float* __restrict__ W3,
                                               bf16* __restrict__ Wt, int n) {
  const float* Ws[4] = {W0, W1, W2, W3};
  const float* W = Ws[blockIdx.z];
  bf16* out = Wt + (size_t)blockIdx.z * n * n;
  __shared__ bf16 t[32][33];
  int bx = blockIdx.x * 32, by = blockIdx.y * 32;
  int tx = threadIdx.x & 31, ty = threadIdx.x >> 5;
#pragma unroll
  for (int i = 0; i < 32; i += 8)
    t[ty + i][tx] = (bf16)W[(size_t)(by + ty + i) * n + bx + tx];
  __syncthreads();
#pragma unroll
  for (int i = 0; i < 32; i += 8)
    out[(size_t)(bx + ty + i) * n + by + tx] = t[tx][ty + i];
}

// ---- transpose V bf16 [b*s][D] -> Vt [bh][hd][2048] ----
// 64x64 tile/block; 16B/lane global reads AND writes (G13); LDS transpose
// with stride-66 rows => both scalar LDS sides are <=2-way (free, m136).
__global__ __launch_bounds__(256) void vtrans(const bf16* __restrict__ V, bf16* __restrict__ Vt) {
  constexpr int Sn = 2048, Dn = 1024;
  __shared__ bf16 L[64 * 66];  // [hd][s], row stride 66
  int s0 = blockIdx.x * 64, bh = blockIdx.y;
  int b = bh >> 4, h = bh & 15;
  int t = threadIdx.x;
  int r = t >> 3, c8 = (t & 7) * 8;
#pragma unroll
  for (int half = 0; half < 2; ++half) {
    int rr = r + half * 32;
    bf16x8 v = *(const bf16x8*)&V[(size_t)(b * Sn + s0 + rr) * Dn + h * 64 + c8];
#pragma unroll
    for (int j = 0; j < 8; ++j) L[(c8 + j) * 66 + rr] = v[j];
  }
  __syncthreads();
  int hd = t >> 3;
#pragma unroll
  for (int half = 0; half < 2; ++half) {
    int hh = hd + half * 32;
    bf16x8 o;
#pragma unroll
    for (int j = 0; j < 8; ++j) o[j] = L[hh * 66 + c8 + j];
    *(bf16x8*)&Vt[(size_t)bh * 64 * Sn + (size_t)hh * Sn + s0 + c8] = o;
  }
}

// ---- GEMM C[M,N] = A[M,K] @ B; register-prefetched k-loop; 3 outputs via blockIdx.y ----
// BT=true path uses fragment-major LDS (flash-proven, r2: conflicts 5.95M->1.62M):
// each MFMA fragment read = one contiguous 1024B block; staging writes XOR-balanced.
// Slot map (byte): [row>>6]<<12 | ((row>>4)&3)<<10 | kchunk<<8 | ((row&15)^kchunk)<<4.
template <typename TA, typename TC, bool BT>
__global__ __launch_bounds__(256) void gemm3(const TA* __restrict__ A,
                                             const void* __restrict__ B0p,
                                             const void* __restrict__ B1p,
                                             const void* __restrict__ B2p,
                                             TC* __restrict__ C0, TC* __restrict__ C1,
                                             TC* __restrict__ C2, int M, int N, int K, int nblk) {
  constexpr int LDA = 40;
  __shared__ bf16 As[BT ? 4096 : 5120];
  __shared__ bf16 Bs[4096];
  int tid = threadIdx.x, wave = tid >> 6, lane = tid & 63;
  int la = lane & 15, quad = lane >> 4;
  int wr = (wave >> 1) * 64, wc = (wave & 1) * 64;
  int by = blockIdx.y;
  int sel = by / nblk;
  int n0 = (by - sel * nblk) * 128;
  const void* Bp = sel == 0 ? B0p : (sel == 1 ? B1p : B2p);
  TC* C = sel == 0 ? C0 : (sel == 1 ? C1 : C2);
  const TA* Ab = A + (size_t)blockIdx.x * 128 * K;
  using TB = typename std::conditional<BT, bf16, float>::type;
  const TB* Bm = (const TB*)Bp;

  // per-p staging indices
  int ar[2], ac[2], br[2], bc[2], swz[2];
  int sq = tid & 3;
#pragma unroll
  for (int p = 0; p < 2; ++p) {
    int li = (tid + p * 256) * 8;
    ar[p] = li >> 5; ac[p] = li & 31;       // A: row, kcol
    if (BT) { br[p] = li >> 5; bc[p] = li & 31; }    // B^T: nrow, kcol
    else    { br[p] = li >> 7; bc[p] = li & 127; }   // B: krow, ncol
    int row = ar[p];
    swz[p] = ((row >> 6) << 12) | (((row >> 4) & 3) << 10) | (sq << 8) |
             ((((row & 15) ^ sq)) << 4);
  }
  // fragment read bases (byte offsets, contiguous 1024B per fragment)
  int rdA = (wave >> 1) * 4096 + quad * 256 + ((la ^ quad) << 4);
  int rdB = (wave & 1) * 4096 + quad * 256 + ((la ^ quad) << 4);

  f32x4 zero = {0.f, 0.f, 0.f, 0.f};
  f32x4 acc[4][4];
#pragma unroll
  for (int i = 0; i < 4; ++i)
#pragma unroll
    for (int j = 0; j < 4; ++j) acc[i][j] = zero;

  decltype(ldr((const TA*)nullptr)) pa[2];
  decltype(ldr((const TB*)nullptr)) pb[2];
#pragma unroll
  for (int p = 0; p < 2; ++p) {
    pa[p] = ldr(&Ab[(size_t)ar[p] * K + ac[p]]);
    if (BT) pb[p] = ldr(&Bm[(size_t)(n0 + br[p]) * K + bc[p]]);
    else    pb[p] = ldr(&Bm[(size_t)br[p] * N + n0 + bc[p]]);
  }

  for (int k0 = 0; k0 < K; k0 += 32) {
#pragma unroll
    for (int p = 0; p < 2; ++p) {
      if constexpr (BT) {
        *(bf16x8*)((char*)As + swz[p]) = cv(pa[p]);
        *(bf16x8*)((char*)Bs + swz[p]) = cv(pb[p]);
      } else {
        *(bf16x8*)&As[ar[p] * LDA + ac[p]] = cv(pa[p]);
        bf16x8 v = cv(pb[p]);
        int kx = br[p] ^ (((bc[p] >> 3) & 3) << 3);
#pragma unroll
        for (int j = 0; j < 8; ++j) Bs[(bc[p] + j) * 32 + kx] = v[j];
      }
    }
    __syncthreads();
    int k1 = k0 + 32;
    if (k1 < K) {
#pragma unroll
      for (int p = 0; p < 2; ++p) {
        pa[p] = ldr(&Ab[(size_t)ar[p] * K + k1 + ac[p]]);
        if (BT) pb[p] = ldr(&Bm[(size_t)(n0 + br[p]) * K + k1 + bc[p]]);
        else    pb[p] = ldr(&Bm[(size_t)(k1 + br[p]) * N + n0 + bc[p]]);
      }
    }
    bf16x8 af[4], bfr[4];
#pragma unroll
    for (int i = 0; i < 4; ++i) {
      if constexpr (BT)
        af[i] = *(const bf16x8*)((const char*)As + rdA + i * 1024);
      else
        af[i] = *(const bf16x8*)&As[(wr + i * 16 + la) * LDA + quad * 8];
    }
#pragma unroll
    for (int j = 0; j < 4; ++j) {
      if constexpr (BT) {
        bfr[j] = *(const bf16x8*)((const char*)Bs + rdB + j * 1024);
      } else {
        int nr = wc + j * 16 + la;
        bfr[j] = *(const bf16x8*)&Bs[nr * 32 + ((quad * 8) ^ (((nr >> 3) & 3) << 3))];
      }
    }
#pragma unroll
    for (int i = 0; i < 4; ++i)
#pragma unroll
      for (int j = 0; j < 4; ++j) acc[i][j] = MFMA16(af[i], bfr[j], acc[i][j]);
    __syncthreads();
  }
#pragma unroll
  for (int i = 0; i < 4; ++i) {
#pragma unroll
    for (int j = 0; j < 4; ++j) {
      int col = n0 + wc + j * 16 + la;
#pragma unroll
      for (int r = 0; r < 4; ++r) {
        int row = blockIdx.x * 128 + wr + i * 16 + quad * 4 + r;
        stC(C, (size_t)row * N + col, acc[i][j][r]);
      }
    }
  }
}

// ---- flash attention, causal, HD=64; transposed scores (S^T = K@Q^T) ----
// grid (1024): one 64-row q-tile per block, big-tiles-first bijective mapping;
// blocks {n, n+256, n+512, n+768} have qts summing to 62 (CU-balanced) and
// share bh within each 32-block run (K/V L2 locality). All 1024 blocks fit
// co-resident (24KB LDS -> 6 blocks/CU), so dispatch order is non-critical.
// Fragment-major LDS: each MFMA fragment read covers one contiguous 1024B
// block (zero read conflicts); XOR slot assignment balances staging writes.
// [round 2 measured: conflicts 5.95M -> 1.62M with this layout]
__global__ __launch_bounds__(256) void flash_attn(const bf16* __restrict__ Q,
                                                  const bf16* __restrict__ Kg,
                                                  const bf16* __restrict__ Vtg,
                                                  bf16* __restrict__ O) {
  constexpr int D = 1024, S = 2048;
  const float MASK = -3.0e4f;
  const float SCL2 = 0.18033688011112042f;  // log2(e)/sqrt(64)
  __shared__ bf16 Ks[4096];  // 8KB fragment-major [nt][kc][quad][la^]
  __shared__ bf16 Vs[4096];  // 8KB fragment-major
  __shared__ bf16 Ps[4096];  // 4 waves x 2KB fragment-major

  int n = blockIdx.x;
  int bh = n & 31;
  int j5 = n >> 5;                        // 0..31
  int j = j5 & 15;
  int qt = (j5 & 16) ? j : 31 - j;        // big-first, bijective, CU-balanced
  int b = bh >> 4, h = bh & 15;
  int tid = threadIdx.x, wave = tid >> 6, lane = tid & 63;
  int la = lane & 15, quad = lane >> 4;
  const size_t base = (size_t)b * S * D + (size_t)h * 64;
  const bf16* Qg = Q + base;
  const bf16* Kb = Kg + base;
  const bf16* Vb = Vtg + (size_t)bh * 64 * S;  // [hd][s]
  int r0 = tid >> 3, c0 = (tid & 7) * 8;  // staging: rows r0,r0+32; col chunk c0

  // LDS element offsets (fragment-major)
  int quads = (tid & 7) & 3, kcs = (tid & 7) >> 2;
  int st0 = (r0 >> 4) * 1024 + kcs * 512 + quads * 128 +
            (((r0 & 15) ^ quads ^ (kcs << 2)) * 8);          // staging write (r0); +2048 for r0+32
  int kvrd0 = quad * 128 + ((la ^ quad) * 8);                // K/V frag read, kc=0 (+ nt*1024)
  int kvrd1 = 512 + quad * 128 + ((la ^ quad ^ 4) * 8);      // kc=1
  int prd0 = wave * 1024 + quad * 128 + ((la ^ ((quad & 1) << 2)) * 8);  // P read kc=0
  int prd1 = prd0 + 512;
  int pwb = wave * 1024 + (quad >> 1) * 128 +
            ((la ^ ((quad >> 1) << 2)) * 8) + (quad & 1) * 4;  // P write (+ nt*256)

  f32x4 zero = {0.f, 0.f, 0.f, 0.f};
  int q0 = qt * 64;
  int ntiles = qt + 1;

  // Q B-frags (pre-scaled by SCL2): lane la holds Q[q0+wave*16+la][quad*8+j]
  bf16x8 aq[2];
  {
    int qrow = q0 + wave * 16 + la;
#pragma unroll
    for (int kc = 0; kc < 2; ++kc) {
      bf16x8 t = *(const bf16x8*)&Qg[(size_t)qrow * D + kc * 32 + quad * 8];
#pragma unroll
      for (int i = 0; i < 8; ++i) t[i] = (bf16)((float)t[i] * SCL2);
      aq[kc] = t;
    }
  }

  f32x4 o[4];
#pragma unroll
  for (int nt = 0; nt < 4; ++nt) o[nt] = zero;
  float m_l = MASK, l_l = 0.f;

  // prefetch tile 0
  bf16x8 kr0 = *(const bf16x8*)&Kb[(size_t)r0 * D + c0];
  bf16x8 kr1 = *(const bf16x8*)&Kb[(size_t)(r0 + 32) * D + c0];
  bf16x8 vr0 = *(const bf16x8*)&Vb[(size_t)r0 * S + c0];
  bf16x8 vr1 = *(const bf16x8*)&Vb[(size_t)(r0 + 32) * S + c0];

  for (int t = 0; t < ntiles; ++t) {
    *(bf16x8*)&Ks[st0] = kr0;
    *(bf16x8*)&Ks[st0 + 2048] = kr1;
    *(bf16x8*)&Vs[st0] = vr0;
    *(bf16x8*)&Vs[st0 + 2048] = vr1;
    __syncthreads();
    if (t + 1 < ntiles) {  // prefetch next tile (latency hidden behind compute)
      int kb2 = (t + 1) * 64;
      kr0 = *(const bf16x8*)&Kb[(size_t)(kb2 + r0) * D + c0];
      kr1 = *(const bf16x8*)&Kb[(size_t)(kb2 + r0 + 32) * D + c0];
      vr0 = *(const bf16x8*)&Vb[(size_t)r0 * S + kb2 + c0];
      vr1 = *(const bf16x8*)&Vb[(size_t)(r0 + 32) * S + kb2 + c0];
    }

    // S^T = K @ Q^T : lane holds S[q=la][key = t*64 + nt*16 + quad*4 + r]
    f32x4 s[4];
    __builtin_amdgcn_s_setprio(1);
#pragma unroll
    for (int nt = 0; nt < 4; ++nt) {
      bf16x8 k0f = *(const bf16x8*)&Ks[nt * 1024 + kvrd0];
      bf16x8 k1f = *(const bf16x8*)&Ks[nt * 1024 + kvrd1];
      f32x4 z = zero;
      z = MFMA16(k0f, aq[0], z);
      z = MFMA16(k1f, aq[1], z);
      s[nt] = z;
    }
    __builtin_amdgcn_s_setprio(0);

    // mask only the diagonal tile
    if (t == qt) {
      int qa = q0 + wave * 16 + la;
      int kb = t * 64;
#pragma unroll
      for (int nt = 0; nt < 4; ++nt)
#pragma unroll
        for (int r = 0; r < 4; ++r) {
          int ka = kb + nt * 16 + quad * 4 + r;
          s[nt][r] = (ka > qa) ? MASK : s[nt][r];
        }
    }

    // online softmax: tree max in-lane over 16 keys, then cross-quad butterfly
    float mx;
    {
      float u0 = fmaxf(fmaxf(s[0][0], s[0][1]), fmaxf(s[0][2], s[0][3]));
      float u1 = fmaxf(fmaxf(s[1][0], s[1][1]), fmaxf(s[1][2], s[1][3]));
      float u2 = fmaxf(fmaxf(s[2][0], s[2][1]), fmaxf(s[2][2], s[2][3]));
      float u3 = fmaxf(fmaxf(s[3][0], s[3][1]), fmaxf(s[3][2], s[3][3]));
      mx = fmaxf(fmaxf(u0, u1), fmaxf(u2, u3));
    }
    mx = fmaxf(mx, m_l);
    mx = fmaxf(mx, __shfl_xor(mx, 16, 64));
    mx = fmaxf(mx, __shfl_xor(mx, 32, 64));

    // defer-max: only rescale when some row's max grew past THR (log2 domain)
    if (!__all(mx - m_l <= 8.0f)) {
      float alpha = __builtin_amdgcn_exp2f(m_l - mx);
      m_l = mx;
      l_l *= alpha;
      float ab[4];
#pragma unroll
      for (int r = 0; r < 4; ++r) ab[r] = __shfl(alpha, quad * 4 + r, 64);
#pragma unroll
      for (int nt = 0; nt < 4; ++nt)
#pragma unroll
        for (int r = 0; r < 4; ++r) o[nt][r] *= ab[r];
    }

    float rs = 0.f;
#pragma unroll
    for (int nt = 0; nt < 4; ++nt) {
      float p0 = __builtin_amdgcn_exp2f(s[nt][0] - m_l);
      float p1 = __builtin_amdgcn_exp2f(s[nt][1] - m_l);
      float p2 = __builtin_amdgcn_exp2f(s[nt][2] - m_l);
      float p3 = __builtin_amdgcn_exp2f(s[nt][3] - m_l);
      s[nt][0] = p0; s[nt][1] = p1; s[nt][2] = p2; s[nt][3] = p3;
      rs += (p0 + p1) + (p2 + p3);
    }
    rs += __shfl_xor(rs, 16, 64);
    rs += __shfl_xor(rs, 32, 64);
    l_l += rs;

    // spill P (wave-private fragment-major; in-wave LDS order + waitcnt safe)
#pragma unroll
    for (int nt = 0; nt < 4; ++nt) {
      bf16x4 pk;
#pragma unroll
      for (int r = 0; r < 4; ++r) pk[r] = (bf16)s[nt][r];
      *(bf16x4*)&Ps[pwb + nt * 256] = pk;
    }

    // O += P @ V
    __builtin_amdgcn_s_setprio(1);
    {
      bf16x8 ap0 = *(const bf16x8*)&Ps[prd0];
#pragma unroll
      for (int nt = 0; nt < 4; ++nt) {
        bf16x8 bv = *(const bf16x8*)&Vs[nt * 1024 + kvrd0];
        o[nt] = MFMA16(ap0, bv, o[nt]);
      }
      bf16x8 ap1 = *(const bf16x8*)&Ps[prd1];
#pragma unroll
      for (int nt = 0; nt < 4; ++nt) {
        bf16x8 bv = *(const bf16x8*)&Vs[nt * 1024 + kvrd1];
        o[nt] = MFMA16(ap1, bv, o[nt]);
      }
    }
    __builtin_amdgcn_s_setprio(0);
    __syncthreads();  // protect Ks/Vs for next tile
  }

  // epilogue: l lives at lane la==row; broadcast, normalize, store
  float inv[4];
#pragma unroll
  for (int r = 0; r < 4; ++r) {
    float lv = __shfl(l_l, quad * 4 + r, 64);
    inv[r] = (lv > 1e-30f) ? 1.0f / lv : 0.0f;
  }
#pragma unroll
  for (int nt = 0; nt < 4; ++nt) {
    int hd = nt * 16 + la;
#pragma unroll
    for (int r = 0; r < 4; ++r) {
      int row = q0 + wave * 16 + quad * 4 + r;
      O[base + (size_t)row * D + hd] = (bf16)(o[nt][r] * inv[r]);
    }
  }
}

extern "C" void kernel_launch(void* const* d_in, const int* in_sizes, int n_in,
                              void* d_out, int out_size, void* d_ws, size_t ws_size,
                              hipStream_t stream) {
  constexpr int B = 2, S = 2048, D = 1024;
  constexpr int M = B * S;
  constexpr size_t WN = (size_t)D * D;
  constexpr size_t XN = (size_t)M * D;

  const float* x = (const float*)d_in[0];
  const float* Wq = (const float*)d_in[1];
  const float* Wk = (const float*)d_in[2];
  const float* Wv = (const float*)d_in[3];
  const float* Wo = (const float*)d_in[4];
  float* out = (float*)d_out;

  if (ws_size < 2 * XN * sizeof(bf16)) return;
  bf16* Qb = (bf16*)d_ws;   // [0,8MB): Q, then O (flash aliases)
  bf16* Vtg = Qb + XN;      // [8,16MB): V^T [bh][hd][s]
  bf16* Wt = Vtg + XN;      // [16,24MB): 4x W^T bf16 (if ws allows)
  bf16* Kb = (bf16*)d_out;  // d_out[0,8MB): K (scratch until final gemm)
  bf16* Vb = Kb + XN;       // d_out[8,16MB): V (dead after vtrans)
  bool use_bt = ws_size >= (2 * XN + 4 * WN) * sizeof(bf16);

  dim3 gq(M / 128, 24), gf(M / 128, 8);
  if (use_bt) {
    prep_wt<<<dim3(32, 32, 4), 256, 0, stream>>>(Wq, Wk, Wv, Wo, Wt, D);
    gemm3<float, bf16, true><<<gq, 256, 0, stream>>>(x, Wt, Wt + WN, Wt + 2 * WN,
                                                     Qb, Kb, Vb, M, D, D, 8);
  } else {
    gemm3<float, bf16, false><<<gq, 256, 0, stream>>>(x, Wq, Wk, Wv, Qb, Kb, Vb, M, D, D, 8);
  }
  vtrans<<<dim3(S / 64, 32), 256, 0, stream>>>(Vb, Vtg);
  flash_attn<<<dim3(1024), 256, 0, stream>>>(Qb, Kb, Vtg, Qb);
  if (use_bt) {
    gemm3<bf16, float, true><<<gf, 256, 0, stream>>>(Qb, Wt + 3 * WN, Wt + 3 * WN, Wt + 3 * WN,
                                                     out, out, out, M, D, D, 8);
  } else {
    gemm3<bf16, float, false><<<gf, 256, 0, stream>>>(Qb, Wo, Wo, Wo, out, out, out, M, D, D, 8);
  }
}